// Round 10
// baseline (82.351 us; speedup 1.0000x reference)
//
#include <hip/hip_runtime.h>
#include <math.h>
#include <stdint.h>

// Problem constants: B=8, S=4096, D=1024, Q=16 -> 32768 rows
#define ROWS_TOTAL 32768
#define DDIM 1024
#define QDIM 16

typedef __attribute__((ext_vector_type(8))) short bf16x8;  // 8 bf16 (4 VGPRs)
typedef __attribute__((ext_vector_type(4))) float f32x4;   // 4 f32

union ABfrag { uint32_t u[4]; bf16x8 v; };

__device__ __forceinline__ uint32_t packhi(uint32_t a, uint32_t b) {
  return __builtin_amdgcn_perm(b, a, 0x07060302u);
}

// ============================================================
// PROBE (diagnostic, this round only): perfectly-coalesced grid-stride
// float4 read of ALL of x, 2 passes, checksum into ws tail.
// Purpose: (a) measure true attainable x-read BW in THIS harness state
// (post-512MiB-ws-fill); (b) test whether reads allocate into L3 (pass 2
// and the following z_kernel both see warm x if so). 2048x256, tiny
// VGPR -> 32 waves/CU. Consumed via per-thread store (no DCE).
// ============================================================
#define PTPB 256
#define PNB  2048
#define PREP 2

__global__ __launch_bounds__(PTPB, 8)
void probe_kernel(const float* __restrict__ x, float* __restrict__ sink) {
  const int tid    = blockIdx.x * PTPB + threadIdx.x;
  const int stride = PTPB * PNB;                 // 524288 threads
  const int n4     = ROWS_TOTAL * DDIM / 4;      // 8,388,608 float4
  const float4* xv = reinterpret_cast<const float4*>(x);
  float acc = 0.f;
#pragma unroll
  for (int rep = 0; rep < PREP; ++rep) {
#pragma unroll
    for (int i = 0; i < n4 / stride; ++i) {      // 16 iters, compile-time
      float4 v = xv[tid + i * stride];
      acc += v.x + v.y + v.z + v.w;
    }
  }
  sink[tid] = acc;
}

// ============================================================
// Kernel Z — EXACT round-7 version (52.8 us total), byte-identical so
// the probe's effect is attributable by subtraction.
// ============================================================
#define ZTPB 512
#define ZWPB 8
#define ZNBLOCKS (ROWS_TOTAL / 16)   // 2048

__global__ __launch_bounds__(ZTPB, 4)
void z_kernel(const float* __restrict__ x, const float* __restrict__ W1,
              const float* __restrict__ b1, const float* __restrict__ theta,
              float* __restrict__ z, int zstride) {
  const int t    = threadIdx.x;
  const int lane = t & 63;
  const int wid  = t >> 6;     // k-slice owner, 0..7
  const int g    = lane >> 4;  // lane-group
  const int q5   = lane & 15;

  __shared__ __align__(16) float xs[16][DDIM];      // 64 KB, swizzled 16B units
  __shared__ __align__(16) float red[ZWPB][64][4];  // 8 KB partial buffer

  const int row0 = blockIdx.x * 16;
  const int kb   = wid * 128;  // this wave's k-base (floats)

  const float bq = b1[q5];
  const float tq = theta[q5];

  // ---- W1 slice: 32 scalar loads (64KB total, L2-hot across blocks)
  float wf[4][8];
#pragma unroll
  for (int s = 0; s < 4; ++s) {
    const float* wp = W1 + (size_t)(kb + 32 * s + 4 * g) * QDIM + q5;
#pragma unroll
    for (int j = 0; j < 4; ++j) wf[s][j] = wp[(size_t)j * QDIM];
#pragma unroll
    for (int j = 0; j < 4; ++j) wf[s][4 + j] = wp[(size_t)(16 + j) * QDIM];
  }

  // ---- stage x: wave w owns rows 2w, 2w+1. 8 contiguous-1KB loads,
  //      then 8 swizzled ds_write_b128 (consumed in issue order).
  float4 st[8];
  {
    const int rs = 2 * wid;
#pragma unroll
    for (int rr = 0; rr < 2; ++rr) {
      const float* xp = x + (size_t)(row0 + rs + rr) * DDIM;
#pragma unroll
      for (int p = 0; p < 4; ++p)
        st[rr * 4 + p] =
            *reinterpret_cast<const float4*>(xp + 4 * (64 * p + lane));
    }
#pragma unroll
    for (int rr = 0; rr < 2; ++rr) {
      const int r = rs + rr;
#pragma unroll
      for (int p = 0; p < 4; ++p) {
        const int u = 64 * p + lane;           // 16B unit within the row
        *reinterpret_cast<float4*>(&xs[r][4 * (u ^ (r & 7))]) =
            st[rr * 4 + p];
      }
    }
  }

  // ---- convert W1 to split-bf16 B-fragments (overlaps other waves' staging)
  ABfrag bhi[4], blo[4];
#pragma unroll
  for (int s = 0; s < 4; ++s) {
    uint32_t u[8], lo[8];
#pragma unroll
    for (int j = 0; j < 8; ++j) {
      u[j]  = __float_as_uint(wf[s][j]);
      lo[j] = __float_as_uint(wf[s][j] - __uint_as_float(u[j] & 0xFFFF0000u));
    }
    bhi[s].u[0] = packhi(u[0], u[1]);   bhi[s].u[1] = packhi(u[2], u[3]);
    bhi[s].u[2] = packhi(u[4], u[5]);   bhi[s].u[3] = packhi(u[6], u[7]);
    blo[s].u[0] = packhi(lo[0], lo[1]); blo[s].u[1] = packhi(lo[2], lo[3]);
    blo[s].u[2] = packhi(lo[4], lo[5]); blo[s].u[3] = packhi(lo[6], lo[7]);
  }

  __syncthreads();  // xs tile visible

  // ---- fragments from LDS: row (lane&15), k-slice units (32wid + 8s + g)
  const int rr = lane & 15;
  const int ub = 32 * wid;
  float4 a0[4], a1[4];
#pragma unroll
  for (int s = 0; s < 4; ++s) {
    a0[s] = *reinterpret_cast<const float4*>(
        &xs[rr][4 * ((ub + 8 * s + g) ^ (rr & 7))]);
    a1[s] = *reinterpret_cast<const float4*>(
        &xs[rr][4 * ((ub + 8 * s + 4 + g) ^ (rr & 7))]);
  }

  // ---- 4 MFMA steps over this wave's k-slice
  f32x4 acc = {0.f, 0.f, 0.f, 0.f};
#pragma unroll
  for (int s = 0; s < 4; ++s) {
    const float fv[8] = {a0[s].x, a0[s].y, a0[s].z, a0[s].w,
                         a1[s].x, a1[s].y, a1[s].z, a1[s].w};
    uint32_t u[8], lo[8];
#pragma unroll
    for (int j = 0; j < 8; ++j) {
      u[j]  = __float_as_uint(fv[j]);
      lo[j] = __float_as_uint(fv[j] - __uint_as_float(u[j] & 0xFFFF0000u));
    }
    ABfrag ahi, alo;
    ahi.u[0] = packhi(u[0], u[1]);   ahi.u[1] = packhi(u[2], u[3]);
    ahi.u[2] = packhi(u[4], u[5]);   ahi.u[3] = packhi(u[6], u[7]);
    alo.u[0] = packhi(lo[0], lo[1]); alo.u[1] = packhi(lo[2], lo[3]);
    alo.u[2] = packhi(lo[4], lo[5]); alo.u[3] = packhi(lo[6], lo[7]);

    acc = __builtin_amdgcn_mfma_f32_16x16x32_bf16(ahi.v, bhi[s].v, acc, 0, 0, 0);
    acc = __builtin_amdgcn_mfma_f32_16x16x32_bf16(alo.v, bhi[s].v, acc, 0, 0, 0);
    acc = __builtin_amdgcn_mfma_f32_16x16x32_bf16(ahi.v, blo[s].v, acc, 0, 0, 0);
  }

  // ---- combine split-K partials (lane-linear 16B: conflict-free)
  *reinterpret_cast<f32x4*>(&red[wid][lane][0]) = acc;
  __syncthreads();

  if (wid == 0) {
    f32x4 s0 = *reinterpret_cast<const f32x4*>(&red[0][lane][0]);
#pragma unroll
    for (int w = 1; w < ZWPB; ++w)
      s0 += *reinterpret_cast<const f32x4*>(&red[w][lane][0]);

    const int r0 = g * 4;
#pragma unroll
    for (int i = 0; i < 4; ++i) {
      const float sv = fmaxf(s0[i] + bq, 0.f) + tq;
      z[(size_t)(row0 + r0 + i) * zstride + q5] = __cosf(sv);
    }
  }
}

// ============================================================
// Kernel O: out[row] = z[row] @ W2 + b2  (unchanged)
// ============================================================
#define OTPB 256
#define ORPB 16
#define ONBLOCKS (ROWS_TOTAL / ORPB)  // 2048

__global__ __launch_bounds__(OTPB, 4)
void o_kernel(const float* z, int zstride, const float* __restrict__ W2,
              const float* __restrict__ b2, float* out) {
  const int t   = threadIdx.x;
  const int col = 4 * t;

  float4 w2r[QDIM];
#pragma unroll
  for (int q = 0; q < QDIM; ++q)
    w2r[q] = *reinterpret_cast<const float4*>(W2 + (size_t)q * DDIM + col);
  const float4 bb = *reinterpret_cast<const float4*>(b2 + col);

  const int row0 = blockIdx.x * ORPB;

  const float* zp0 = z + (size_t)row0 * zstride;
  float4 zc0 = *reinterpret_cast<const float4*>(zp0 + 0);
  float4 zc1 = *reinterpret_cast<const float4*>(zp0 + 4);
  float4 zc2 = *reinterpret_cast<const float4*>(zp0 + 8);
  float4 zc3 = *reinterpret_cast<const float4*>(zp0 + 12);

#pragma unroll
  for (int r = 0; r < ORPB; ++r) {
    float4 zn0 = zc0, zn1 = zc1, zn2 = zc2, zn3 = zc3;
    if (r + 1 < ORPB) {
      const float* znp = z + (size_t)(row0 + r + 1) * zstride;
      zn0 = *reinterpret_cast<const float4*>(znp + 0);
      zn1 = *reinterpret_cast<const float4*>(znp + 4);
      zn2 = *reinterpret_cast<const float4*>(znp + 8);
      zn3 = *reinterpret_cast<const float4*>(znp + 12);
    }

    const float zv[16] = {zc0.x, zc0.y, zc0.z, zc0.w,
                          zc1.x, zc1.y, zc1.z, zc1.w,
                          zc2.x, zc2.y, zc2.z, zc2.w,
                          zc3.x, zc3.y, zc3.z, zc3.w};
    float4 acc = bb;
#pragma unroll
    for (int q = 0; q < QDIM; ++q) {
      acc.x = fmaf(zv[q], w2r[q].x, acc.x);
      acc.y = fmaf(zv[q], w2r[q].y, acc.y);
      acc.z = fmaf(zv[q], w2r[q].z, acc.z);
      acc.w = fmaf(zv[q], w2r[q].w, acc.w);
    }
    *reinterpret_cast<float4*>(out + (size_t)(row0 + r) * DDIM + col) = acc;

    zc0 = zn0; zc1 = zn1; zc2 = zn2; zc3 = zn3;
  }
}

extern "C" void kernel_launch(void* const* d_in, const int* in_sizes, int n_in,
                              void* d_out, int out_size, void* d_ws, size_t ws_size,
                              hipStream_t stream) {
  const float* x     = (const float*)d_in[0];
  const float* W1    = (const float*)d_in[1];
  const float* b1    = (const float*)d_in[2];
  const float* theta = (const float*)d_in[3];
  const float* W2    = (const float*)d_in[4];
  const float* b2    = (const float*)d_in[5];
  float* out = (float*)d_out;

  const size_t zbytes = (size_t)ROWS_TOTAL * QDIM * sizeof(float);  // 2 MB
  float* zbuf;
  int zstride;
  if (d_ws != nullptr && ws_size >= zbytes) {
    zbuf = (float*)d_ws;  // compact z in workspace
    zstride = QDIM;
  } else {
    zbuf = out;           // fallback: stash z in out[row][0:16]
    zstride = DDIM;
  }

  // ---- diagnostic probe (this round): sink at ws+384MiB, clear of zbuf
  const size_t sink_off = (size_t)384 << 20;
  const size_t sink_sz  = (size_t)PTPB * PNB * sizeof(float);  // 2 MB
  if (d_ws != nullptr && ws_size >= sink_off + sink_sz) {
    float* sink = (float*)((char*)d_ws + sink_off);
    probe_kernel<<<dim3(PNB), dim3(PTPB), 0, stream>>>(x, sink);
  }

  z_kernel<<<dim3(ZNBLOCKS), dim3(ZTPB), 0, stream>>>(x, W1, b1, theta, zbuf, zstride);
  o_kernel<<<dim3(ONBLOCKS), dim3(OTPB), 0, stream>>>(zbuf, zstride, W2, b2, out);
}

// Round 11
// 54.280 us; speedup vs baseline: 1.5172x; 1.5172x over previous
//
#include <hip/hip_runtime.h>
#include <math.h>
#include <stdint.h>

// Problem constants: B=8, S=4096, D=1024, Q=16 -> 32768 rows
#define ROWS_TOTAL 32768
#define DDIM 1024
#define QDIM 16

typedef __attribute__((ext_vector_type(8))) short bf16x8;  // 8 bf16 (4 VGPRs)
typedef __attribute__((ext_vector_type(4))) float f32x4;   // 4 f32

union ABfrag { uint32_t u[4]; bf16x8 v; };

// pack the high 16 bits (truncated bf16) of two f32 bit patterns:
// result low ushort = a.hi16 (lower-k element), high ushort = b.hi16
__device__ __forceinline__ uint32_t packhi(uint32_t a, uint32_t b) {
  return __builtin_amdgcn_perm(b, a, 0x07060302u);
}

// ============================================================
// FUSED kernel: out[row] = cos(relu(x[row]@W1+b1)+theta) @ W2 + b2
//
// Model (r10 probe + r1..r9 evidence): pure-READ BW on this box caps at
// ~3 TB/s (per-CU outstanding-line cap x HBM latency; fills/writes do
// 7 TB/s). z-phase is at ~92% of that cap -> the remaining serial cost
// is o_kernel's ~5us. Fuse mm2 as a per-block epilogue: its VALU+store
// work hides under the read-stall cycles the cap forces anyway.
//
// Phase 1 (r7-z verbatim): stage x tile (16 rows) via contiguous-1KB
//   loads + XOR-swizzled ds_write; W1 k-slice per wave in registers
//   (split-bf16); 12 MFMA (16x16x32) split-K across 8 waves; LDS reduce;
//   wave 0: bias/relu/theta/cos -> zs[16][16] in LDS (was global).
// Phase 2 (r0-proven mm2): thread owns out cols 2t..2t+1; W2 loaded
//   AFTER the MFMA phase (L2-hot, latency overlaps reduce) so z-phase
//   register pressure is unchanged; zs reads are all-lane broadcasts
//   (conflict-free); coalesced float2 stores (L3-absorbed).
// Fragment maps (verified r4-r10, random data):
//   A: lane l -> row l&15; B: lane l -> col l&15 (same k-perm both);
//   C: lane l -> D[(l>>4)*4+i][l&15]
// LDS 73KB -> 2 blocks/CU; 3 barriers/block.
// ============================================================
#define TPB 512
#define WPB 8
#define NBLOCKS (ROWS_TOTAL / 16)   // 2048

__global__ __launch_bounds__(TPB, 4)
void fused_kernel(const float* __restrict__ x, const float* __restrict__ W1,
                  const float* __restrict__ b1, const float* __restrict__ theta,
                  const float* __restrict__ W2, const float* __restrict__ b2,
                  float* __restrict__ out) {
  const int t    = threadIdx.x;
  const int lane = t & 63;
  const int wid  = t >> 6;     // k-slice owner, 0..7
  const int g    = lane >> 4;  // lane-group
  const int q5   = lane & 15;

  __shared__ __align__(16) float xs[16][DDIM];      // 64 KB, swizzled 16B units
  __shared__ __align__(16) float red[WPB][64][4];   // 8 KB split-K partials
  __shared__ __align__(16) float zs[16][QDIM];      // 1 KB z tile

  const int row0 = blockIdx.x * 16;
  const int kb   = wid * 128;  // this wave's k-base (floats)

  const float bq = b1[q5];
  const float tq = theta[q5];

  // ---- W1 slice: 32 scalar loads (64KB total, L2-hot across blocks)
  float wf[4][8];
#pragma unroll
  for (int s = 0; s < 4; ++s) {
    const float* wp = W1 + (size_t)(kb + 32 * s + 4 * g) * QDIM + q5;
#pragma unroll
    for (int j = 0; j < 4; ++j) wf[s][j] = wp[(size_t)j * QDIM];
#pragma unroll
    for (int j = 0; j < 4; ++j) wf[s][4 + j] = wp[(size_t)(16 + j) * QDIM];
  }

  // ---- stage x: wave w owns rows 2w, 2w+1. 8 contiguous-1KB loads,
  //      then 8 swizzled ds_write_b128 (consumed in issue order).
  float4 st[8];
  {
    const int rs = 2 * wid;
#pragma unroll
    for (int rr = 0; rr < 2; ++rr) {
      const float* xp = x + (size_t)(row0 + rs + rr) * DDIM;
#pragma unroll
      for (int p = 0; p < 4; ++p)
        st[rr * 4 + p] =
            *reinterpret_cast<const float4*>(xp + 4 * (64 * p + lane));
    }
#pragma unroll
    for (int rr = 0; rr < 2; ++rr) {
      const int r = rs + rr;
#pragma unroll
      for (int p = 0; p < 4; ++p) {
        const int u = 64 * p + lane;           // 16B unit within the row
        *reinterpret_cast<float4*>(&xs[r][4 * (u ^ (r & 7))]) =
            st[rr * 4 + p];
      }
    }
  }

  // ---- convert W1 to split-bf16 B-fragments (overlaps other waves' staging)
  ABfrag bhi[4], blo[4];
#pragma unroll
  for (int s = 0; s < 4; ++s) {
    uint32_t u[8], lo[8];
#pragma unroll
    for (int j = 0; j < 8; ++j) {
      u[j]  = __float_as_uint(wf[s][j]);
      lo[j] = __float_as_uint(wf[s][j] - __uint_as_float(u[j] & 0xFFFF0000u));
    }
    bhi[s].u[0] = packhi(u[0], u[1]);   bhi[s].u[1] = packhi(u[2], u[3]);
    bhi[s].u[2] = packhi(u[4], u[5]);   bhi[s].u[3] = packhi(u[6], u[7]);
    blo[s].u[0] = packhi(lo[0], lo[1]); blo[s].u[1] = packhi(lo[2], lo[3]);
    blo[s].u[2] = packhi(lo[4], lo[5]); blo[s].u[3] = packhi(lo[6], lo[7]);
  }

  __syncthreads();  // xs tile visible

  // ---- fragments from LDS: row (lane&15), k-slice units (32wid + 8s + g)
  const int rr = lane & 15;
  const int ub = 32 * wid;
  float4 a0[4], a1[4];
#pragma unroll
  for (int s = 0; s < 4; ++s) {
    a0[s] = *reinterpret_cast<const float4*>(
        &xs[rr][4 * ((ub + 8 * s + g) ^ (rr & 7))]);
    a1[s] = *reinterpret_cast<const float4*>(
        &xs[rr][4 * ((ub + 8 * s + 4 + g) ^ (rr & 7))]);
  }

  // ---- 4 MFMA steps over this wave's k-slice
  f32x4 acc = {0.f, 0.f, 0.f, 0.f};
#pragma unroll
  for (int s = 0; s < 4; ++s) {
    const float fv[8] = {a0[s].x, a0[s].y, a0[s].z, a0[s].w,
                         a1[s].x, a1[s].y, a1[s].z, a1[s].w};
    uint32_t u[8], lo[8];
#pragma unroll
    for (int j = 0; j < 8; ++j) {
      u[j]  = __float_as_uint(fv[j]);
      lo[j] = __float_as_uint(fv[j] - __uint_as_float(u[j] & 0xFFFF0000u));
    }
    ABfrag ahi, alo;
    ahi.u[0] = packhi(u[0], u[1]);   ahi.u[1] = packhi(u[2], u[3]);
    ahi.u[2] = packhi(u[4], u[5]);   ahi.u[3] = packhi(u[6], u[7]);
    alo.u[0] = packhi(lo[0], lo[1]); alo.u[1] = packhi(lo[2], lo[3]);
    alo.u[2] = packhi(lo[4], lo[5]); alo.u[3] = packhi(lo[6], lo[7]);

    acc = __builtin_amdgcn_mfma_f32_16x16x32_bf16(ahi.v, bhi[s].v, acc, 0, 0, 0);
    acc = __builtin_amdgcn_mfma_f32_16x16x32_bf16(alo.v, bhi[s].v, acc, 0, 0, 0);
    acc = __builtin_amdgcn_mfma_f32_16x16x32_bf16(ahi.v, blo[s].v, acc, 0, 0, 0);
  }

  // ---- W2/b2 per-thread loads issued HERE: z-phase registers are dead
  //      or dying, latency overlaps the reduce/cos below. Coalesced
  //      float2 (64 lanes x 8B = 512B/instr), L2-hot across blocks.
  float2 w2r[QDIM];
#pragma unroll
  for (int q = 0; q < QDIM; ++q)
    w2r[q] = *reinterpret_cast<const float2*>(W2 + (size_t)q * DDIM + 2 * t);
  const float2 bb = *reinterpret_cast<const float2*>(b2 + 2 * t);

  // ---- combine split-K partials (lane-linear 16B: conflict-free)
  *reinterpret_cast<f32x4*>(&red[wid][lane][0]) = acc;
  __syncthreads();

  if (wid == 0) {
    f32x4 s0 = *reinterpret_cast<const f32x4*>(&red[0][lane][0]);
#pragma unroll
    for (int w = 1; w < WPB; ++w)
      s0 += *reinterpret_cast<const f32x4*>(&red[w][lane][0]);

    const int r0 = g * 4;
#pragma unroll
    for (int i = 0; i < 4; ++i) {
      const float sv = fmaxf(s0[i] + bq, 0.f) + tq;
      zs[r0 + i][q5] = __cosf(sv);
    }
  }
  __syncthreads();  // zs visible to all waves

  // ---- mm2 epilogue: thread owns out cols 2t..2t+1 for all 16 rows.
  //      zs reads are same-address across the wave -> LDS broadcast.
#pragma unroll
  for (int r = 0; r < 16; ++r) {
    float o0 = bb.x, o1 = bb.y;
#pragma unroll
    for (int jb = 0; jb < 4; ++jb) {
      const float4 zv = *reinterpret_cast<const float4*>(&zs[r][4 * jb]);
      o0 = fmaf(zv.x, w2r[4 * jb + 0].x, o0);
      o1 = fmaf(zv.x, w2r[4 * jb + 0].y, o1);
      o0 = fmaf(zv.y, w2r[4 * jb + 1].x, o0);
      o1 = fmaf(zv.y, w2r[4 * jb + 1].y, o1);
      o0 = fmaf(zv.z, w2r[4 * jb + 2].x, o0);
      o1 = fmaf(zv.z, w2r[4 * jb + 2].y, o1);
      o0 = fmaf(zv.w, w2r[4 * jb + 3].x, o0);
      o1 = fmaf(zv.w, w2r[4 * jb + 3].y, o1);
    }
    *reinterpret_cast<float2*>(out + (size_t)(row0 + r) * DDIM + 2 * t) =
        make_float2(o0, o1);
  }
}

extern "C" void kernel_launch(void* const* d_in, const int* in_sizes, int n_in,
                              void* d_out, int out_size, void* d_ws, size_t ws_size,
                              hipStream_t stream) {
  const float* x     = (const float*)d_in[0];
  const float* W1    = (const float*)d_in[1];
  const float* b1    = (const float*)d_in[2];
  const float* theta = (const float*)d_in[3];
  const float* W2    = (const float*)d_in[4];
  const float* b2    = (const float*)d_in[5];
  float* out = (float*)d_out;

  fused_kernel<<<dim3(NBLOCKS), dim3(TPB), 0, stream>>>(x, W1, b1, theta, W2,
                                                        b2, out);
}

// Round 12
// 53.821 us; speedup vs baseline: 1.5301x; 1.0085x over previous
//
#include <hip/hip_runtime.h>
#include <math.h>
#include <stdint.h>

// Problem constants: B=8, S=4096, D=1024, Q=16 -> 32768 rows
#define ROWS_TOTAL 32768
#define DDIM 1024
#define QDIM 16

typedef __attribute__((ext_vector_type(8))) short bf16x8;  // 8 bf16 (4 VGPRs)
typedef __attribute__((ext_vector_type(4))) float f32x4;   // 4 f32

union ABfrag { uint32_t u[4]; bf16x8 v; };

// pack the high 16 bits (truncated bf16) of two f32 bit patterns:
// result low ushort = a.hi16 (lower-k element), high ushort = b.hi16
__device__ __forceinline__ uint32_t packhi(uint32_t a, uint32_t b) {
  return __builtin_amdgcn_perm(b, a, 0x07060302u);
}

// async global->LDS DMA, 16B per lane. LDS dest = wave-uniform base +
// lane*16 (hardware-fixed); global src is PER-LANE (pre-swizzled).
__device__ __forceinline__ void gload_lds16(const float* src, float* lds_dst) {
  __builtin_amdgcn_global_load_lds(
      (const __attribute__((address_space(1))) void*)src,
      (__attribute__((address_space(3))) void*)lds_dst, 16, 0, 0);
}

// ============================================================
// Kernel Z (MFMA, split-K, DMA-staged x): round-7 structure with ONE
// change: x staging uses global_load_lds (width=16) instead of
// float4-load + ds_write. Rationale (r10 probe + r1-r11 counters):
// every VGPR-return read structure converges to ~2.8-3.7 TB/s while
// writes do 7 TB/s -> suspected per-CU outstanding-credit cap on the
// VGPR-return path; the LDS-DMA path is the one untested mechanism.
//
//   - Staging: wave w stages rows 2w,2w+1; 8 DMA instrs (1KB each).
//     LDS stays LINEAR per chunk; the r7 XOR swizzle moves to the
//     GLOBAL source (lane l sources unit 64p + (l^(r&7)) — same lines,
//     shuffled within 128B). Resulting LDS content is bit-identical to
//     r7, so fragment reads are unchanged.
//   - __syncthreads() drains vmcnt(0) -> DMA completion guaranteed.
//   - W1 slice in registers (L2-hot scalar loads), split-bf16
//     (acc += Ahi*Bhi + Alo*Bhi + Ahi*Blo), 4 MFMA steps/wave,
//     8KB LDS split-K reduce, wave0 cos epilogue.
// Fragment maps (verified r4-r11, random data):
//   A: lane l -> row l&15; B: lane l -> col l&15 (same k-perm both);
//   C: lane l -> D[(l>>4)*4+i][l&15]
// ============================================================
#define ZTPB 512
#define ZWPB 8
#define ZNBLOCKS (ROWS_TOTAL / 16)   // 2048

__global__ __launch_bounds__(ZTPB, 4)
void z_kernel(const float* __restrict__ x, const float* __restrict__ W1,
              const float* __restrict__ b1, const float* __restrict__ theta,
              float* __restrict__ z, int zstride) {
  const int t    = threadIdx.x;
  const int lane = t & 63;
  const int wid  = t >> 6;     // k-slice owner, 0..7
  const int g    = lane >> 4;  // lane-group
  const int q5   = lane & 15;

  __shared__ __align__(16) float xs[16][DDIM];      // 64 KB (swizzled content)
  __shared__ __align__(16) float red[ZWPB][64][4];  // 8 KB partial buffer

  const int row0 = blockIdx.x * 16;
  const int kb   = wid * 128;  // this wave's k-base (floats)

  const float bq = b1[q5];
  const float tq = theta[q5];

  // ---- stage x FIRST (DMA -> LDS, no VGPR round-trip). Wave w owns
  //      rows 2w,2w+1; 4 chunks of 1KB per row; source pre-swizzled so
  //      LDS unit v of row r holds x unit v^(r&7) (same as r7's layout).
  {
    const int rs = 2 * wid;
#pragma unroll
    for (int rr = 0; rr < 2; ++rr) {
      const int r = rs + rr;
      const float* xp = x + (size_t)(row0 + r) * DDIM;
      const int ls = lane ^ (r & 7);   // swizzled lane-unit within chunk
#pragma unroll
      for (int p = 0; p < 4; ++p)
        gload_lds16(xp + 4 * (64 * p + ls), &xs[r][4 * (64 * p)]);
    }
  }

  // ---- W1 slice: 32 scalar loads (64KB total, L2-hot across blocks)
  float wf[4][8];
#pragma unroll
  for (int s = 0; s < 4; ++s) {
    const float* wp = W1 + (size_t)(kb + 32 * s + 4 * g) * QDIM + q5;
#pragma unroll
    for (int j = 0; j < 4; ++j) wf[s][j] = wp[(size_t)j * QDIM];
#pragma unroll
    for (int j = 0; j < 4; ++j) wf[s][4 + j] = wp[(size_t)(16 + j) * QDIM];
  }

  // ---- convert W1 to split-bf16 B-fragments (overlaps DMA in flight)
  ABfrag bhi[4], blo[4];
#pragma unroll
  for (int s = 0; s < 4; ++s) {
    uint32_t u[8], lo[8];
#pragma unroll
    for (int j = 0; j < 8; ++j) {
      u[j]  = __float_as_uint(wf[s][j]);
      lo[j] = __float_as_uint(wf[s][j] - __uint_as_float(u[j] & 0xFFFF0000u));
    }
    bhi[s].u[0] = packhi(u[0], u[1]);   bhi[s].u[1] = packhi(u[2], u[3]);
    bhi[s].u[2] = packhi(u[4], u[5]);   bhi[s].u[3] = packhi(u[6], u[7]);
    blo[s].u[0] = packhi(lo[0], lo[1]); blo[s].u[1] = packhi(lo[2], lo[3]);
    blo[s].u[2] = packhi(lo[4], lo[5]); blo[s].u[3] = packhi(lo[6], lo[7]);
  }

  __syncthreads();  // drains vmcnt(0): DMA complete, xs visible

  // ---- fragments from LDS: row (lane&15), k-slice units (32wid + 8s + g)
  const int rr = lane & 15;
  const int ub = 32 * wid;
  float4 a0[4], a1[4];
#pragma unroll
  for (int s = 0; s < 4; ++s) {
    a0[s] = *reinterpret_cast<const float4*>(
        &xs[rr][4 * ((ub + 8 * s + g) ^ (rr & 7))]);
    a1[s] = *reinterpret_cast<const float4*>(
        &xs[rr][4 * ((ub + 8 * s + 4 + g) ^ (rr & 7))]);
  }

  // ---- 4 MFMA steps over this wave's k-slice
  f32x4 acc = {0.f, 0.f, 0.f, 0.f};
#pragma unroll
  for (int s = 0; s < 4; ++s) {
    const float fv[8] = {a0[s].x, a0[s].y, a0[s].z, a0[s].w,
                         a1[s].x, a1[s].y, a1[s].z, a1[s].w};
    uint32_t u[8], lo[8];
#pragma unroll
    for (int j = 0; j < 8; ++j) {
      u[j]  = __float_as_uint(fv[j]);
      lo[j] = __float_as_uint(fv[j] - __uint_as_float(u[j] & 0xFFFF0000u));
    }
    ABfrag ahi, alo;
    ahi.u[0] = packhi(u[0], u[1]);   ahi.u[1] = packhi(u[2], u[3]);
    ahi.u[2] = packhi(u[4], u[5]);   ahi.u[3] = packhi(u[6], u[7]);
    alo.u[0] = packhi(lo[0], lo[1]); alo.u[1] = packhi(lo[2], lo[3]);
    alo.u[2] = packhi(lo[4], lo[5]); alo.u[3] = packhi(lo[6], lo[7]);

    acc = __builtin_amdgcn_mfma_f32_16x16x32_bf16(ahi.v, bhi[s].v, acc, 0, 0, 0);
    acc = __builtin_amdgcn_mfma_f32_16x16x32_bf16(alo.v, bhi[s].v, acc, 0, 0, 0);
    acc = __builtin_amdgcn_mfma_f32_16x16x32_bf16(ahi.v, blo[s].v, acc, 0, 0, 0);
  }

  // ---- combine split-K partials (lane-linear 16B: conflict-free)
  *reinterpret_cast<f32x4*>(&red[wid][lane][0]) = acc;
  __syncthreads();

  if (wid == 0) {
    f32x4 s0 = *reinterpret_cast<const f32x4*>(&red[0][lane][0]);
#pragma unroll
    for (int w = 1; w < ZWPB; ++w)
      s0 += *reinterpret_cast<const f32x4*>(&red[w][lane][0]);

    const int r0 = g * 4;
#pragma unroll
    for (int i = 0; i < 4; ++i) {
      const float sv = fmaxf(s0[i] + bq, 0.f) + tq;
      z[(size_t)(row0 + r0 + i) * zstride + q5] = __cosf(sv);
    }
  }
}

// ============================================================
// Kernel O: out[row] = z[row] @ W2 + b2  (unchanged; ~5 us)
//   z/out intentionally NOT __restrict__ (aliased fallback).
// ============================================================
#define OTPB 256
#define ORPB 16
#define ONBLOCKS (ROWS_TOTAL / ORPB)  // 2048

__global__ __launch_bounds__(OTPB, 4)
void o_kernel(const float* z, int zstride, const float* __restrict__ W2,
              const float* __restrict__ b2, float* out) {
  const int t   = threadIdx.x;
  const int col = 4 * t;

  float4 w2r[QDIM];
#pragma unroll
  for (int q = 0; q < QDIM; ++q)
    w2r[q] = *reinterpret_cast<const float4*>(W2 + (size_t)q * DDIM + col);
  const float4 bb = *reinterpret_cast<const float4*>(b2 + col);

  const int row0 = blockIdx.x * ORPB;

  const float* zp0 = z + (size_t)row0 * zstride;
  float4 zc0 = *reinterpret_cast<const float4*>(zp0 + 0);
  float4 zc1 = *reinterpret_cast<const float4*>(zp0 + 4);
  float4 zc2 = *reinterpret_cast<const float4*>(zp0 + 8);
  float4 zc3 = *reinterpret_cast<const float4*>(zp0 + 12);

#pragma unroll
  for (int r = 0; r < ORPB; ++r) {
    float4 zn0 = zc0, zn1 = zc1, zn2 = zc2, zn3 = zc3;
    if (r + 1 < ORPB) {
      const float* znp = z + (size_t)(row0 + r + 1) * zstride;
      zn0 = *reinterpret_cast<const float4*>(znp + 0);
      zn1 = *reinterpret_cast<const float4*>(znp + 4);
      zn2 = *reinterpret_cast<const float4*>(znp + 8);
      zn3 = *reinterpret_cast<const float4*>(znp + 12);
    }

    const float zv[16] = {zc0.x, zc0.y, zc0.z, zc0.w,
                          zc1.x, zc1.y, zc1.z, zc1.w,
                          zc2.x, zc2.y, zc2.z, zc2.w,
                          zc3.x, zc3.y, zc3.z, zc3.w};
    float4 acc = bb;
#pragma unroll
    for (int q = 0; q < QDIM; ++q) {
      acc.x = fmaf(zv[q], w2r[q].x, acc.x);
      acc.y = fmaf(zv[q], w2r[q].y, acc.y);
      acc.z = fmaf(zv[q], w2r[q].z, acc.z);
      acc.w = fmaf(zv[q], w2r[q].w, acc.w);
    }
    *reinterpret_cast<float4*>(out + (size_t)(row0 + r) * DDIM + col) = acc;

    zc0 = zn0; zc1 = zn1; zc2 = zn2; zc3 = zn3;
  }
}

extern "C" void kernel_launch(void* const* d_in, const int* in_sizes, int n_in,
                              void* d_out, int out_size, void* d_ws, size_t ws_size,
                              hipStream_t stream) {
  const float* x     = (const float*)d_in[0];
  const float* W1    = (const float*)d_in[1];
  const float* b1    = (const float*)d_in[2];
  const float* theta = (const float*)d_in[3];
  const float* W2    = (const float*)d_in[4];
  const float* b2    = (const float*)d_in[5];
  float* out = (float*)d_out;

  const size_t zbytes = (size_t)ROWS_TOTAL * QDIM * sizeof(float);  // 2 MB
  float* zbuf;
  int zstride;
  if (d_ws != nullptr && ws_size >= zbytes) {
    zbuf = (float*)d_ws;  // compact z in workspace
    zstride = QDIM;
  } else {
    zbuf = out;           // fallback: stash z in out[row][0:16]
    zstride = DDIM;
  }

  z_kernel<<<dim3(ZNBLOCKS), dim3(ZTPB), 0, stream>>>(x, W1, b1, theta, zbuf, zstride);
  o_kernel<<<dim3(ONBLOCKS), dim3(OTPB), 0, stream>>>(zbuf, zstride, W2, b2, out);
}